// Round 9
// baseline (279.888 us; speedup 1.0000x reference)
//
#include <hip/hip_runtime.h>
#include <hip/hip_bf16.h>

typedef __hip_bfloat16 bf16;
typedef unsigned int uint32;
typedef __attribute__((ext_vector_type(8))) short short8;
typedef __attribute__((ext_vector_type(4))) float float4v;
typedef __attribute__((ext_vector_type(16))) float float16v;

#define THREADS 512
#define LDX 520  // sX row stride in bf16 (16B-aligned rows for ds_read_b128)
#define LDE 68   // sE row stride in f32 (17 dw*4: float4-aligned, odd/4 phase)

__device__ __forceinline__ bf16 f2b(float x) { return __float2bfloat16(x); }
__device__ __forceinline__ uint32 packbf2(float x, float y) {
  union { __hip_bfloat162 b; uint32 u; } cv;
  cv.b = __float22bfloat162_rn(make_float2(x, y));
  return cv.u;
}

// All three W (f32, K x M row-major) -> bf16 in 32x32x16 MFMA-B-frag order:
// dst[((kb*M + n)*2 + q)*8 + j] with k = kb*16 + q*8 + j. Outputs concatenated.
__global__ void convw_all(const float* __restrict__ W1,
                          const float* __restrict__ W2,
                          const float* __restrict__ W3, bf16* __restrict__ dst) {
  int o = blockIdx.x * 256 + threadIdx.x;
  if (o >= 409600) return;
  const float* W;
  int Mlog, loc;
  if (o < 16384) { W = W1; Mlog = 9; loc = o; }
  else if (o < 278528) { W = W2; Mlog = 9; loc = o - 16384; }
  else { W = W3; Mlog = 8; loc = o - 278528; }
  int j = loc & 7, q = (loc >> 3) & 1, rest = loc >> 4;
  int M = 1 << Mlog;
  int n = rest & (M - 1), kb = rest >> Mlog;
  int k = kb * 16 + q * 8 + j;
  dst[o] = f2b(W[(size_t)k * M + n]);
}

// Extra 16-col B tiles (16x16x32 layout): cols 0..7 = W@a_src per head,
// 8..15 = W@a_dst. Per layer: [ks][n(16)][kc(4)][j(8)]; concat (512|8192|8192).
__global__ void convE_all(
    const float* __restrict__ W1, const float* __restrict__ as1, const float* __restrict__ ad1,
    const float* __restrict__ W2, const float* __restrict__ as2, const float* __restrict__ ad2,
    const float* __restrict__ W3, const float* __restrict__ as3, const float* __restrict__ ad3,
    bf16* __restrict__ dstE) {
  int o = blockIdx.x * 256 + threadIdx.x;
  if (o >= 16896) return;
  const float *W, *as_, *ad_;
  int M, C, loc;
  if (o < 512) { loc = o; W = W1; as_ = as1; ad_ = ad1; M = 512; C = 64; }
  else if (o < 8704) { loc = o - 512; W = W2; as_ = as2; ad_ = ad2; M = 512; C = 64; }
  else { loc = o - 8704; W = W3; as_ = as3; ad_ = ad3; M = 256; C = 32; }
  int j = loc & 7, kc = (loc >> 3) & 3, n = (loc >> 5) & 15, ks = loc >> 9;
  int k = ks * 32 + kc * 8 + j;
  int head = n & 7;
  const float* a = (n < 8) ? as_ : ad_;
  float s = 0.f;
  for (int c = 0; c < C; ++c)
    s += W[(size_t)k * M + head * C + c] * a[head * C + c];
  dstE[o] = f2b(s);
}

// One GAT layer on 32x32x16 MFMA. Wave w == head w (owns C output cols).
// rt-outer phase 1 (32 accs live); h kept in regs as packed bf16 (Ppk);
// C/D -> B-frag transpose is a per-dword q-half exchange (shfl_xor 32).
template <int K, int M, int C, bool LAST>
__device__ __forceinline__ void gat_layer(
    int t, const bf16* __restrict__ Wswz, const bf16* __restrict__ WE,
    const float* __restrict__ bias, bf16* sX, float* sE) {
  constexpr int NCT = C / 32;   // 32-col tiles per wave (2 or 1)
  constexpr int KS16 = K / 16;  // 32x32x16 k-steps
  constexpr int KSE = K / 32;   // 16x16x32 k-steps for E
  const int lane = t & 63;
  const int hu = __builtin_amdgcn_readfirstlane(t >> 6);  // wave/head id
  const int c = lane & 31, q = lane >> 5;
  const int ln16 = lane & 15, kq16 = lane >> 4;
  const int colbase = hu * C;

  // ---- E-tile (ls|ld for ALL heads), waves 0-3, 16x16x32 path ----
  if (hu < 4) {
    float4v acce = (float4v)0.f;
#pragma unroll
    for (int ks = 0; ks < KSE; ++ks) {
      short8 afrE = *(const short8*)(sX + (hu * 16 + ln16) * LDX + ks * 32 + kq16 * 8);
      short8 efr = *(const short8*)(WE + ks * 512 + ln16 * 32 + kq16 * 8);
      acce = __builtin_amdgcn_mfma_f32_16x16x32_bf16(afrE, efr, acce, 0, 0, 0);
    }
    // C/D: col=ln16 (as/ad idx), row=kq16*4+r (local node) -> sE[col][node]
    *(float4v*)(sE + ln16 * LDE + hu * 16 + kq16 * 4) = acce;
  }

  // ---- phase 1: h = x@W (32x32x16), rt-outer: A-reads halved, B re-read ----
  uint32 Ppk[NCT][4][4];  // [ct][kstep t][U0,U1,V0,V1] packed bf16x2
#pragma unroll
  for (int rt = 0; rt < 2; ++rt) {
    float16v acc[NCT];
#pragma unroll
    for (int ct = 0; ct < NCT; ++ct) acc[ct] = (float16v)0.f;
    const bf16* ap = sX + (rt * 32 + c) * LDX + q * 8;
#pragma unroll 4
    for (int ks = 0; ks < KS16; ++ks) {
      short8 afr = *(const short8*)(ap + ks * 16);
#pragma unroll
      for (int ct = 0; ct < NCT; ++ct) {
        short8 bfr = *(const short8*)(Wswz + (size_t)ks * (M * 16) +
                                      ((colbase + ct * 32 + c) * 2 + q) * 8);
        acc[ct] = __builtin_amdgcn_mfma_f32_32x32x16_bf16(afr, bfr, acc[ct], 0, 0, 0);
      }
    }
    // pack h to bf16x2 pairs; acc dies here. C/D row=(r&3)+8*(r>>2)+4q (verified).
#pragma unroll
    for (int ct = 0; ct < NCT; ++ct)
#pragma unroll
      for (int tp = 0; tp < 2; ++tp) {
        Ppk[ct][rt * 2 + tp][0] = packbf2(acc[ct][8 * tp + 0], acc[ct][8 * tp + 1]);
        Ppk[ct][rt * 2 + tp][1] = packbf2(acc[ct][8 * tp + 2], acc[ct][8 * tp + 3]);
        Ppk[ct][rt * 2 + tp][2] = packbf2(acc[ct][8 * tp + 4], acc[ct][8 * tp + 5]);
        Ppk[ct][rt * 2 + tp][3] = packbf2(acc[ct][8 * tp + 6], acc[ct][8 * tp + 7]);
      }
  }

  __syncthreads();  // sX readers done; sE complete

  // ---- P rows in 32x32 A-frag regs; row i = rt*32 + c; k node = t*16+q*8+j ----
  const float* lsrow = sE + hu * LDE;
  const float* ldrow = sE + (8 + hu) * LDE;
  short8 pfr[2][4];
#pragma unroll
  for (int rt = 0; rt < 2; ++rt) {
    const float ldi = ldrow[rt * 32 + c];
    float pe_[4][8];
    float rsum = 0.f;
#pragma unroll
    for (int tt = 0; tt < 4; ++tt) {
      float4 v0 = *(const float4*)(lsrow + tt * 16 + q * 8);
      float4 v1 = *(const float4*)(lsrow + tt * 16 + q * 8 + 4);
      float ls8[8] = {v0.x, v0.y, v0.z, v0.w, v1.x, v1.y, v1.z, v1.w};
#pragma unroll
      for (int jj = 0; jj < 8; ++jj) {
        float tv = ldi + ls8[jj];
        float l = fmaxf(tv, 0.2f * tv);
        float e = __expf(l);
        pe_[tt][jj] = e;
        rsum += e;
      }
    }
    rsum += __shfl_xor(rsum, 32, 64);
    const float ri = 1.0f / rsum;
#pragma unroll
    for (int tt = 0; tt < 4; ++tt) {
      union { uint32 d[4]; short8 s; } w;
#pragma unroll
      for (int jp = 0; jp < 4; ++jp)
        w.d[jp] = packbf2(pe_[tt][2 * jp] * ri, pe_[tt][2 * jp + 1] * ri);
      pfr[rt][tt] = w.s;
    }
  }

  // ---- per-ct: h C/D -> B-frag (q-half exchange), O = P@h, bias, store ----
  // Dest kstep t, lane (c,q'), dword jd: node R = t*16+q'*8+2jd(+1), col c.
  // Source: tile rt=t>>1, lane (c, q_src=jd>>1), regs r=(2jd&3)+8(t&1)+4q'.
  // => q'=0 frag: [U0,U1, partner's U0,U1]; q'=1: [partner's V0,V1, V0,V1].
#pragma unroll
  for (int ct = 0; ct < NCT; ++ct) {
    short8 hfr[4];
#pragma unroll
    for (int tt = 0; tt < 4; ++tt) {
      uint32 U0 = Ppk[ct][tt][0], U1 = Ppk[ct][tt][1];
      uint32 V0 = Ppk[ct][tt][2], V1 = Ppk[ct][tt][3];
      uint32 X0 = q ? U0 : V0;
      uint32 X1 = q ? U1 : V1;
      uint32 R0 = (uint32)__shfl_xor((int)X0, 32, 64);
      uint32 R1 = (uint32)__shfl_xor((int)X1, 32, 64);
      union { uint32 d[4]; short8 s; } u;
      u.d[0] = q ? R0 : U0;
      u.d[1] = q ? R1 : U1;
      u.d[2] = q ? V0 : R0;
      u.d[3] = q ? V1 : R1;
      hfr[tt] = u.s;
    }
    float16v oacc[2];
    oacc[0] = (float16v)0.f;
    oacc[1] = (float16v)0.f;
#pragma unroll
    for (int tt = 0; tt < 4; ++tt) {
      oacc[0] = __builtin_amdgcn_mfma_f32_32x32x16_bf16(pfr[0][tt], hfr[tt], oacc[0], 0, 0, 0);
      oacc[1] = __builtin_amdgcn_mfma_f32_32x32x16_bf16(pfr[1][tt], hfr[tt], oacc[1], 0, 0, 0);
    }
    const float bv = bias[colbase + ct * 32 + c];
#pragma unroll
    for (int rt = 0; rt < 2; ++rt)
#pragma unroll
      for (int r = 0; r < 16; ++r) {
        float val = oacc[rt][r] + bv;
        int row = rt * 32 + (r & 3) + 8 * (r >> 2) + 4 * q;
        if constexpr (LAST)
          ((float*)sX)[row * 260 + colbase + ct * 32 + c] = val;
        else
          sX[row * LDX + colbase + ct * 32 + c] = f2b(val);
      }
  }
  __syncthreads();  // x' complete before next layer / mean
}

__global__ __launch_bounds__(THREADS, 4) void gat3_mfma(
    const float* __restrict__ xs, const float* __restrict__ pe,
    const bf16* __restrict__ W1s, const bf16* __restrict__ WE1,
    const float* __restrict__ b1, const bf16* __restrict__ W2s,
    const bf16* __restrict__ WE2, const float* __restrict__ b2,
    const bf16* __restrict__ W3s, const bf16* __restrict__ WE3,
    const float* __restrict__ b3, float* __restrict__ out) {
  extern __shared__ char smem[];
  bf16* sX = (bf16*)smem;              // 64*520*2 = 66560 B
  float* sE = (float*)(smem + 66560);  // 16*68*4 = 4352 B -> total 70912

  const int t = threadIdx.x;
  const int blk = blockIdx.x;  // bs*R = 2048 graphs
  const int bidx = blk >> 8;   // batch index (R=256)

  // x0 = concat(xs, broadcast pos_enc) -> [64][32] bf16, stride LDX
  for (int idx = t; idx < 64 * 32; idx += THREADS) {
    int n = idx >> 5, f = idx & 31;
    float v = (f == 0) ? xs[blk * 64 + n] : pe[(bidx * 64 + n) * 31 + (f - 1)];
    sX[n * LDX + f] = f2b(v);
  }
  __syncthreads();

  gat_layer<32, 512, 64, false>(t, W1s, WE1, b1, sX, sE);
  gat_layer<512, 512, 64, false>(t, W2s, WE2, b2, sX, sE);
  gat_layer<512, 256, 32, true>(t, W3s, WE3, b3, sX, sE);

  // mean over 64 nodes -> [256]
  const float* xf = (const float*)sX;
  if (t < 256) {
    float s = 0.f;
#pragma unroll 8
    for (int i = 0; i < 64; ++i) s += xf[i * 260 + t];
    out[blk * 256 + t] = s * 0.015625f;
  }
}

extern "C" void kernel_launch(void* const* d_in, const int* in_sizes, int n_in,
                              void* d_out, int out_size, void* d_ws, size_t ws_size,
                              hipStream_t stream) {
  const float* xs = (const float*)d_in[0];
  const float* pe = (const float*)d_in[1];
  const float* W1 = (const float*)d_in[2];
  const float* as1 = (const float*)d_in[3];
  const float* ad1 = (const float*)d_in[4];
  const float* b1 = (const float*)d_in[5];
  const float* W2 = (const float*)d_in[6];
  const float* as2 = (const float*)d_in[7];
  const float* ad2 = (const float*)d_in[8];
  const float* b2 = (const float*)d_in[9];
  const float* W3 = (const float*)d_in[10];
  const float* as3 = (const float*)d_in[11];
  const float* ad3 = (const float*)d_in[12];
  const float* b3 = (const float*)d_in[13];

  bf16* Wall = (bf16*)d_ws;          // 409600 elems
  bf16* WEall = Wall + 409600;       // 16896 elems (total 852992 B)
  bf16* W1s = Wall;
  bf16* W2s = Wall + 16384;
  bf16* W3s = Wall + 278528;
  bf16* WE1 = WEall;
  bf16* WE2 = WEall + 512;
  bf16* WE3 = WEall + 8704;

  convw_all<<<dim3(1600), dim3(256), 0, stream>>>(W1, W2, W3, Wall);
  convE_all<<<dim3(66), dim3(256), 0, stream>>>(W1, as1, ad1, W2, as2, ad2,
                                                W3, as3, ad3, WEall);

  const size_t smem = 70912;
  (void)hipFuncSetAttribute((const void*)gat3_mfma,
                            hipFuncAttributeMaxDynamicSharedMemorySize,
                            (int)smem);
  gat3_mfma<<<dim3(2048), dim3(THREADS), smem, stream>>>(
      xs, pe, W1s, WE1, b1, W2s, WE2, b2, W3s, WE3, b3, (float*)d_out);
}

// Round 10
// 249.660 us; speedup vs baseline: 1.1211x; 1.1211x over previous
//
#include <hip/hip_runtime.h>
#include <hip/hip_bf16.h>

typedef __hip_bfloat16 bf16;
typedef unsigned int uint32;
typedef __attribute__((ext_vector_type(8))) short short8;
typedef __attribute__((ext_vector_type(4))) float float4v;
typedef __attribute__((ext_vector_type(16))) float float16v;

#define THREADS 512
#define LDX 520  // sX row stride in bf16 (16B-aligned rows for ds_read_b128)
#define LDE 68   // sE row stride in f32

__device__ __forceinline__ bf16 f2b(float x) { return __float2bfloat16(x); }
__device__ __forceinline__ uint32 packbf2(float x, float y) {
  union { __hip_bfloat162 b; uint32 u; } cv;
  cv.b = __float22bfloat162_rn(make_float2(x, y));
  return cv.u;
}

// All three W (f32, K x M row-major) -> bf16 in 32x32x16 MFMA-B-frag order:
// dst[((kb*M + n)*2 + q)*8 + j] with k = kb*16 + q*8 + j. Outputs concatenated.
__global__ void convw_all(const float* __restrict__ W1,
                          const float* __restrict__ W2,
                          const float* __restrict__ W3, bf16* __restrict__ dst) {
  int o = blockIdx.x * 256 + threadIdx.x;
  if (o >= 409600) return;
  const float* W;
  int Mlog, loc;
  if (o < 16384) { W = W1; Mlog = 9; loc = o; }
  else if (o < 278528) { W = W2; Mlog = 9; loc = o - 16384; }
  else { W = W3; Mlog = 8; loc = o - 278528; }
  int j = loc & 7, q = (loc >> 3) & 1, rest = loc >> 4;
  int M = 1 << Mlog;
  int n = rest & (M - 1), kb = rest >> Mlog;
  int k = kb * 16 + q * 8 + j;
  dst[o] = f2b(W[(size_t)k * M + n]);
}

// Extra 16-col B tiles (16x16x32 layout): cols 0..7 = W@a_src per head,
// 8..15 = W@a_dst. Per layer: [ks][n(16)][kc(4)][j(8)]; concat (512|8192|8192).
__global__ void convE_all(
    const float* __restrict__ W1, const float* __restrict__ as1, const float* __restrict__ ad1,
    const float* __restrict__ W2, const float* __restrict__ as2, const float* __restrict__ ad2,
    const float* __restrict__ W3, const float* __restrict__ as3, const float* __restrict__ ad3,
    bf16* __restrict__ dstE) {
  int o = blockIdx.x * 256 + threadIdx.x;
  if (o >= 16896) return;
  const float *W, *as_, *ad_;
  int M, C, loc;
  if (o < 512) { loc = o; W = W1; as_ = as1; ad_ = ad1; M = 512; C = 64; }
  else if (o < 8704) { loc = o - 512; W = W2; as_ = as2; ad_ = ad2; M = 512; C = 64; }
  else { loc = o - 8704; W = W3; as_ = as3; ad_ = ad3; M = 256; C = 32; }
  int j = loc & 7, kc = (loc >> 3) & 3, n = (loc >> 5) & 15, ks = loc >> 9;
  int k = ks * 32 + kc * 8 + j;
  int head = n & 7;
  const float* a = (n < 8) ? as_ : ad_;
  float s = 0.f;
  for (int c = 0; c < C; ++c)
    s += W[(size_t)k * M + head * C + c] * a[head * C + c];
  dstE[o] = f2b(s);
}

// One GAT layer on 32x32x16 MFMA. Wave w == head w (owns C output cols).
// Phase 1 single-pass: all 4 acc chains (64 regs) live; each A/B fragment
// loaded exactly once. h kept in regs as packed bf16 (Ppk); C/D -> B-frag
// transpose is a per-dword q-half exchange (shfl_xor 32).
template <int K, int M, int C, bool LAST>
__device__ __forceinline__ void gat_layer(
    int t, const bf16* __restrict__ Wswz, const bf16* __restrict__ WE,
    const float* __restrict__ bias, bf16* sX, float* sE) {
  constexpr int NCT = C / 32;   // 32-col tiles per wave (2 or 1)
  constexpr int KS16 = K / 16;  // 32x32x16 k-steps
  constexpr int KSE = K / 32;   // 16x16x32 k-steps for E
  const int lane = t & 63;
  const int hu = __builtin_amdgcn_readfirstlane(t >> 6);  // wave/head id
  const int c = lane & 31, q = lane >> 5;
  const int ln16 = lane & 15, kq16 = lane >> 4;
  const int colbase = hu * C;

  // ---- E-tile (ls|ld for ALL heads), waves 0-3, 16x16x32 path ----
  if (hu < 4) {
    float4v acce = (float4v)0.f;
#pragma unroll
    for (int ks = 0; ks < KSE; ++ks) {
      short8 afrE = *(const short8*)(sX + (hu * 16 + ln16) * LDX + ks * 32 + kq16 * 8);
      short8 efr = *(const short8*)(WE + ks * 512 + ln16 * 32 + kq16 * 8);
      acce = __builtin_amdgcn_mfma_f32_16x16x32_bf16(afrE, efr, acce, 0, 0, 0);
    }
    // C/D: col=ln16 (as/ad idx), row=kq16*4+r (local node) -> sE[col][node]
    *(float4v*)(sE + ln16 * LDE + hu * 16 + kq16 * 4) = acce;
  }

  // ---- phase 1: h = x@W (32x32x16), single pass, 2rt x NCT acc chains ----
  uint32 Ppk[NCT][4][4];  // [ct][kstep t][U0,U1,V0,V1] packed bf16x2
  {
    float16v acc[2][NCT];
#pragma unroll
    for (int rt = 0; rt < 2; ++rt)
#pragma unroll
      for (int ct = 0; ct < NCT; ++ct) acc[rt][ct] = (float16v)0.f;
    const bf16* ap = sX + c * LDX + q * 8;
    const bf16* bp = Wswz + ((colbase + c) * 2 + q) * 8;
#pragma unroll 4
    for (int ks = 0; ks < KS16; ++ks) {
      short8 afr[2];
      afr[0] = *(const short8*)(ap + ks * 16);
      afr[1] = *(const short8*)(ap + 32 * LDX + ks * 16);
      short8 bfr[NCT];
#pragma unroll
      for (int ct = 0; ct < NCT; ++ct)
        bfr[ct] = *(const short8*)(bp + (size_t)ks * (M * 16) + ct * 32 * 16);
#pragma unroll
      for (int rt = 0; rt < 2; ++rt)
#pragma unroll
        for (int ct = 0; ct < NCT; ++ct)
          acc[rt][ct] = __builtin_amdgcn_mfma_f32_32x32x16_bf16(
              afr[rt], bfr[ct], acc[rt][ct], 0, 0, 0);
    }
    // pack h to bf16x2 pairs; acc dies here. C/D row=(r&3)+8*(r>>2)+4q.
#pragma unroll
    for (int rt = 0; rt < 2; ++rt)
#pragma unroll
      for (int ct = 0; ct < NCT; ++ct)
#pragma unroll
        for (int tp = 0; tp < 2; ++tp) {
          Ppk[ct][rt * 2 + tp][0] = packbf2(acc[rt][ct][8 * tp + 0], acc[rt][ct][8 * tp + 1]);
          Ppk[ct][rt * 2 + tp][1] = packbf2(acc[rt][ct][8 * tp + 2], acc[rt][ct][8 * tp + 3]);
          Ppk[ct][rt * 2 + tp][2] = packbf2(acc[rt][ct][8 * tp + 4], acc[rt][ct][8 * tp + 5]);
          Ppk[ct][rt * 2 + tp][3] = packbf2(acc[rt][ct][8 * tp + 6], acc[rt][ct][8 * tp + 7]);
        }
  }

  __syncthreads();  // sX readers done; sE complete

  // ---- P rows in 32x32 A-frag regs; row i = rt*32 + c; k node = t*16+q*8+j ----
  const float* lsrow = sE + hu * LDE;
  const float* ldrow = sE + (8 + hu) * LDE;
  short8 pfr[2][4];
#pragma unroll
  for (int rt = 0; rt < 2; ++rt) {
    const float ldi = ldrow[rt * 32 + c];
    float pe_[4][8];
    float rsum = 0.f;
#pragma unroll
    for (int tt = 0; tt < 4; ++tt) {
      float4 v0 = *(const float4*)(lsrow + tt * 16 + q * 8);
      float4 v1 = *(const float4*)(lsrow + tt * 16 + q * 8 + 4);
      float ls8[8] = {v0.x, v0.y, v0.z, v0.w, v1.x, v1.y, v1.z, v1.w};
#pragma unroll
      for (int jj = 0; jj < 8; ++jj) {
        float tv = ldi + ls8[jj];
        float l = fmaxf(tv, 0.2f * tv);
        float e = __expf(l);
        pe_[tt][jj] = e;
        rsum += e;
      }
    }
    rsum += __shfl_xor(rsum, 32, 64);
    const float ri = 1.0f / rsum;
#pragma unroll
    for (int tt = 0; tt < 4; ++tt) {
      union { uint32 d[4]; short8 s; } w;
#pragma unroll
      for (int jp = 0; jp < 4; ++jp)
        w.d[jp] = packbf2(pe_[tt][2 * jp] * ri, pe_[tt][2 * jp + 1] * ri);
      pfr[rt][tt] = w.s;
    }
  }

  // ---- per-ct: h C/D -> B-frag (q-half exchange), O = P@h, bias, store ----
  // Dest kstep t, lane (c,q'), dword jd: node R = t*16+q'*8+2jd(+1), col c.
  // => q'=0 frag: [U0,U1, partner's U0,U1]; q'=1: [partner's V0,V1, V0,V1].
#pragma unroll
  for (int ct = 0; ct < NCT; ++ct) {
    short8 hfr[4];
#pragma unroll
    for (int tt = 0; tt < 4; ++tt) {
      uint32 U0 = Ppk[ct][tt][0], U1 = Ppk[ct][tt][1];
      uint32 V0 = Ppk[ct][tt][2], V1 = Ppk[ct][tt][3];
      uint32 X0 = q ? U0 : V0;
      uint32 X1 = q ? U1 : V1;
      uint32 R0 = (uint32)__shfl_xor((int)X0, 32, 64);
      uint32 R1 = (uint32)__shfl_xor((int)X1, 32, 64);
      union { uint32 d[4]; short8 s; } u;
      u.d[0] = q ? R0 : U0;
      u.d[1] = q ? R1 : U1;
      u.d[2] = q ? V0 : R0;
      u.d[3] = q ? V1 : R1;
      hfr[tt] = u.s;
    }
    float16v oacc[2];
    oacc[0] = (float16v)0.f;
    oacc[1] = (float16v)0.f;
#pragma unroll
    for (int tt = 0; tt < 4; ++tt) {
      oacc[0] = __builtin_amdgcn_mfma_f32_32x32x16_bf16(pfr[0][tt], hfr[tt], oacc[0], 0, 0, 0);
      oacc[1] = __builtin_amdgcn_mfma_f32_32x32x16_bf16(pfr[1][tt], hfr[tt], oacc[1], 0, 0, 0);
    }
    const float bv = bias[colbase + ct * 32 + c];
#pragma unroll
    for (int rt = 0; rt < 2; ++rt)
#pragma unroll
      for (int r = 0; r < 16; ++r) {
        float val = oacc[rt][r] + bv;
        int row = rt * 32 + (r & 3) + 8 * (r >> 2) + 4 * q;
        if constexpr (LAST)
          ((float*)sX)[row * 260 + colbase + ct * 32 + c] = val;
        else
          sX[row * LDX + colbase + ct * 32 + c] = f2b(val);
      }
  }
  __syncthreads();  // x' complete before next layer / mean
}

__global__ __launch_bounds__(THREADS, 4) void gat3_mfma(
    const float* __restrict__ xs, const float* __restrict__ pe,
    const bf16* __restrict__ W1s, const bf16* __restrict__ WE1,
    const float* __restrict__ b1, const bf16* __restrict__ W2s,
    const bf16* __restrict__ WE2, const float* __restrict__ b2,
    const bf16* __restrict__ W3s, const bf16* __restrict__ WE3,
    const float* __restrict__ b3, float* __restrict__ out) {
  extern __shared__ char smem[];
  bf16* sX = (bf16*)smem;              // 64*520*2 = 66560 B
  float* sE = (float*)(smem + 66560);  // 16*68*4 = 4352 B -> total 70912

  const int t = threadIdx.x;
  const int blk = blockIdx.x;  // bs*R = 2048 graphs
  const int bidx = blk >> 8;   // batch index (R=256)

  // x0 = concat(xs, broadcast pos_enc) -> [64][32] bf16, stride LDX
  for (int idx = t; idx < 64 * 32; idx += THREADS) {
    int n = idx >> 5, f = idx & 31;
    float v = (f == 0) ? xs[blk * 64 + n] : pe[(bidx * 64 + n) * 31 + (f - 1)];
    sX[n * LDX + f] = f2b(v);
  }
  __syncthreads();

  gat_layer<32, 512, 64, false>(t, W1s, WE1, b1, sX, sE);
  gat_layer<512, 512, 64, false>(t, W2s, WE2, b2, sX, sE);
  gat_layer<512, 256, 32, true>(t, W3s, WE3, b3, sX, sE);

  // mean over 64 nodes -> [256]
  const float* xf = (const float*)sX;
  if (t < 256) {
    float s = 0.f;
#pragma unroll 8
    for (int i = 0; i < 64; ++i) s += xf[i * 260 + t];
    out[blk * 256 + t] = s * 0.015625f;
  }
}

extern "C" void kernel_launch(void* const* d_in, const int* in_sizes, int n_in,
                              void* d_out, int out_size, void* d_ws, size_t ws_size,
                              hipStream_t stream) {
  const float* xs = (const float*)d_in[0];
  const float* pe = (const float*)d_in[1];
  const float* W1 = (const float*)d_in[2];
  const float* as1 = (const float*)d_in[3];
  const float* ad1 = (const float*)d_in[4];
  const float* b1 = (const float*)d_in[5];
  const float* W2 = (const float*)d_in[6];
  const float* as2 = (const float*)d_in[7];
  const float* ad2 = (const float*)d_in[8];
  const float* b2 = (const float*)d_in[9];
  const float* W3 = (const float*)d_in[10];
  const float* as3 = (const float*)d_in[11];
  const float* ad3 = (const float*)d_in[12];
  const float* b3 = (const float*)d_in[13];

  bf16* Wall = (bf16*)d_ws;          // 409600 elems
  bf16* WEall = Wall + 409600;       // 16896 elems (total 852992 B)
  bf16* W1s = Wall;
  bf16* W2s = Wall + 16384;
  bf16* W3s = Wall + 278528;
  bf16* WE1 = WEall;
  bf16* WE2 = WEall + 512;
  bf16* WE3 = WEall + 8704;

  convw_all<<<dim3(1600), dim3(256), 0, stream>>>(W1, W2, W3, Wall);
  convE_all<<<dim3(66), dim3(256), 0, stream>>>(W1, as1, ad1, W2, as2, ad2,
                                                W3, as3, ad3, WEall);

  const size_t smem = 70912;
  (void)hipFuncSetAttribute((const void*)gat3_mfma,
                            hipFuncAttributeMaxDynamicSharedMemorySize,
                            (int)smem);
  gat3_mfma<<<dim3(2048), dim3(THREADS), smem, stream>>>(
      xs, pe, W1s, WE1, b1, W2s, WE2, b2, W3s, WE3, b3, (float*)d_out);
}